// Round 3
// baseline (422.945 us; speedup 1.0000x reference)
//
#include <hip/hip_runtime.h>
#include <cstdint>

#define B_    128
#define T_    2048
#define NIN_  16
#define NH_   128
#define NOUT_ 5

#define ALPHA_I_ 0.75f
#define ALPHA_V_ 0.96875f
#define THETA_   64.0f

#define SB_STRIDE_ 68   // u32 words per (b,c) spike-bit row: 2 guard + 64 data + 2 guard

__device__ __forceinline__ float mulrn(float a, float b) { return __fmul_rn(a, b); }
__device__ __forceinline__ float addrn(float a, float b) { return __fadd_rn(a, b); }

// ---------------------------------------------------------------------------
// prep: weight_norm (x64 folded in; layers 2,3 stored TRANSPOSED [c][o]),
// packed delay tables efo[c] = {bitcast(e), f, 1-f, 0} with e = floor(d)+1
// (folding delay_shift1), zero the 3 count slots of d_out.
// ---------------------------------------------------------------------------
__global__ void prep_kernel(const float* __restrict__ fc1_v, const float* __restrict__ fc1_g,
                            const float* __restrict__ fc2_v, const float* __restrict__ fc2_g,
                            const float* __restrict__ fc3_v, const float* __restrict__ fc3_g,
                            const float* __restrict__ delay1, const float* __restrict__ delay2,
                            float* __restrict__ w1s, float* __restrict__ w2sT, float* __restrict__ w3sT,
                            float4* __restrict__ efo1, float4* __restrict__ efo2,
                            float* __restrict__ counts) {
  int tid = threadIdx.x;
  if (tid < NH_) {
    // layer 1 row (kept [o][c] for gemm1)
    {
      float ss = 0.f;
      for (int c = 0; c < NIN_; c++) { float v = fc1_v[tid * NIN_ + c]; ss = __fmaf_rn(v, v, ss); }
      float nrm = sqrtf(ss);
      float g = fc1_g[tid];
      for (int c = 0; c < NIN_; c++)
        w1s[tid * NIN_ + c] = 64.0f * __fdiv_rn(mulrn(g, fc1_v[tid * NIN_ + c]), nrm);
    }
    // layer 2 row, stored transposed
    {
      float ss = 0.f;
      for (int c = 0; c < NH_; c++) { float v = fc2_v[tid * NH_ + c]; ss = __fmaf_rn(v, v, ss); }
      float nrm = sqrtf(ss);
      float g = fc2_g[tid];
      for (int c = 0; c < NH_; c++)
        w2sT[c * NH_ + tid] = 64.0f * __fdiv_rn(mulrn(g, fc2_v[tid * NH_ + c]), nrm);
    }
    // delay tables
    {
      float d1 = delay1[tid];
      float fl = floorf(d1);
      float f = __fsub_rn(d1, fl);
      efo1[tid] = make_float4(__int_as_float((int)fl + 1), f, __fsub_rn(1.0f, f), 0.f);
      float d2 = delay2[tid];
      float fl2 = floorf(d2);
      float f2v = __fsub_rn(d2, fl2);
      efo2[tid] = make_float4(__int_as_float((int)fl2 + 1), f2v, __fsub_rn(1.0f, f2v), 0.f);
    }
  }
  if (tid < NOUT_) {
    float ss = 0.f;
    for (int c = 0; c < NH_; c++) { float v = fc3_v[tid * NH_ + c]; ss = __fmaf_rn(v, v, ss); }
    float nrm = sqrtf(ss);
    float g = fc3_g[tid];
    for (int c = 0; c < NH_; c++)
      w3sT[c * NOUT_ + tid] = 64.0f * __fdiv_rn(mulrn(g, fc3_v[tid * NH_ + c]), nrm);
  }
  if (tid < 3) counts[tid] = 0.f;
}

// ---------------------------------------------------------------------------
// gemm1: z[b,o,t] = sum_c w1s[o,c] * x[b,c,t]
// ---------------------------------------------------------------------------
__global__ __launch_bounds__(256) void gemm1_kernel(const float* __restrict__ x,
                                                    const float* __restrict__ w1s,
                                                    float* __restrict__ z) {
  __shared__ float w[NH_ * NIN_];
  int tid = threadIdx.x;
  for (int i = tid; i < NH_ * NIN_; i += 256) w[i] = w1s[i];
  __syncthreads();
  int t = blockIdx.x * 256 + tid;
  int b = blockIdx.y;
  const float* xp = x + (size_t)b * NIN_ * T_ + t;
  float xv[NIN_];
#pragma unroll
  for (int c = 0; c < NIN_; c++) xv[c] = xp[(size_t)c * T_];
  float* zp = z + (size_t)b * NH_ * T_ + t;
  for (int o = 0; o < NH_; o++) {
    float acc = 0.f;
#pragma unroll
    for (int c = 0; c < NIN_; c++) acc = __fmaf_rn(w[o * NIN_ + c], xv[c], acc);
    zp[(size_t)o * T_] = acc;
  }
}

// ---------------------------------------------------------------------------
// gemm with fused axon-delay gather, BITPACKED spike input (guarded rows).
// Each thread: 2 contiguous t's, OT outputs. Weights broadcast from LDS
// (transposed [c][OT] tile); bit windows straight from global (L2-resident,
// guard words make all loads unconditional); delay params via uniform
// s_load of packed float4.  grid (T/512, O/OT, B), block 256.
// ---------------------------------------------------------------------------
template <int OT>
__global__ __launch_bounds__(256, 4) void gemm_delay_bits2_kernel(
    const uint32_t* __restrict__ sbits, const float* __restrict__ wT,
    const float4* __restrict__ efo_tab, float* __restrict__ z, int o_count) {
  __shared__ float s_w[NH_ * OT];  // s_w[c*OT+oo]
  int tid = threadIdx.x;
  int tb = blockIdx.x * 512;
  int otile = blockIdx.y * OT;
  int b = blockIdx.z;

  for (int i = tid; i < NH_ * OT; i += 256) {
    int c = i / OT, oo = i - c * OT;
    s_w[i] = wT[c * o_count + otile + oo];   // coalesced (wT is [c][o])
  }
  __syncthreads();

  int t0 = tb + tid * 2;
  const uint32_t* sb_row = sbits + (size_t)b * NH_ * SB_STRIDE_;

  float acc[OT][2];
#pragma unroll
  for (int oo = 0; oo < OT; oo++) { acc[oo][0] = 0.f; acc[oo][1] = 0.f; }

  for (int c = 0; c < NH_; c++) {
    const float4 efo = efo_tab[c];           // uniform -> s_load_dwordx4
    const int e = __float_as_int(efo.x);
    const float f = efo.y, omf = efo.z;
    const uint32_t* gb = sb_row + (size_t)c * SB_STRIDE_;
    int bitpos = t0 - e - 1;                 // in [-12, 2045]
    int wi = bitpos >> 5;                    // in [-1, 63]
    int sh = bitpos & 31;
    uint32_t lo = gb[2 + wi];                // guards zero out-of-range words
    uint32_t hi = gb[3 + wi];
    uint32_t Sl = (uint32_t)(((((unsigned long long)hi << 32) | lo)) >> sh);
    float b0 = (float)(Sl & 1u);             // s[t0-e-1]
    float b1 = (float)((Sl >> 1) & 1u);      // s[t0-e] == s[(t0+1)-e-1]
    float b2 = (float)((Sl >> 2) & 1u);      // s[(t0+1)-e]
    float val0 = __fmaf_rn(omf, b1, __fmul_rn(f, b0));
    float val1 = __fmaf_rn(omf, b2, __fmul_rn(f, b1));
#pragma unroll
    for (int oo = 0; oo < OT; oo++) {
      float w = s_w[c * OT + oo];            // uniform -> LDS broadcast b128s
      acc[oo][0] = __fmaf_rn(w, val0, acc[oo][0]);
      acc[oo][1] = __fmaf_rn(w, val1, acc[oo][1]);
    }
  }

#pragma unroll
  for (int oo = 0; oo < OT; oo++) {
    float* zp = z + ((size_t)b * o_count + otile + oo) * T_ + t0;
    *(float2*)zp = make_float2(acc[oo][0], acc[oo][1]);
  }
}

// ---------------------------------------------------------------------------
// Loihi scan, bitpacked u32 output (UNSHIFTED, guarded stride-68 rows).
// One thread per (b,o) row; 64-t groups, 4 rotating prefetch buffers.
// count = popcount(all bits) - bit[T-1].
// ---------------------------------------------------------------------------
__global__ __launch_bounds__(64, 1) void scan_bits_kernel(const float* __restrict__ z,
                                                          uint32_t* __restrict__ sbits,
                                                          float* __restrict__ cnt) {
  int row = blockIdx.x * 64 + threadIdx.x;
  const float4* zp4 = (const float4*)(z + (size_t)row * T_);
  uint32_t* sp = sbits + (size_t)row * SB_STRIDE_;

  // zero guard words (0,1) and (66,67)
  *(uint2*)sp = make_uint2(0u, 0u);
  *(uint2*)(sp + 66) = make_uint2(0u, 0u);
  uint2* dp = (uint2*)(sp + 2);

  float u = 0.f, v = 0.f;
  int ci = 0;
  unsigned long long mlast = 0;
  float4 buf[4][16];

#pragma unroll
  for (int i = 0; i < 16; i++) buf[0][i] = zp4[i];
#pragma unroll
  for (int i = 0; i < 16; i++) buf[1][i] = zp4[16 + i];

#pragma unroll 4
  for (int g = 0; g < 32; g++) {
    int gl = g + 2 > 31 ? 31 : g + 2;
#pragma unroll
    for (int i = 0; i < 16; i++) buf[(g + 2) & 3][i] = zp4[gl * 16 + i];

    unsigned long long m = 0;
#pragma unroll
    for (int i = 0; i < 16; i++) {
      float4 cv = buf[g & 3][i];
      float zv[4] = {cv.x, cv.y, cv.z, cv.w};
#pragma unroll
      for (int j = 0; j < 4; j++) {
        u = addrn(mulrn(ALPHA_I_, u), zv[j]);
        v = addrn(mulrn(ALPHA_V_, v), u);
        bool sb = (v >= THETA_);
        v = sb ? 0.f : v;
        m |= sb ? (1ull << (i * 4 + j)) : 0ull;
      }
    }
    dp[g] = make_uint2((uint32_t)m, (uint32_t)(m >> 32));
    ci += __popcll(m);
    mlast = m;
  }
  ci -= (int)(mlast >> 63);  // exclude t = T-1 (delay_shift1 drops it)

  float c = (float)ci;
  for (int off = 32; off; off >>= 1) c += __shfl_down(c, off, 64);
  if (threadIdx.x == 0) atomicAdd(cnt, c);
}

// ---------------------------------------------------------------------------
// Loihi scan, f32 SHIFTED output straight into d_out (layer 3).
// ---------------------------------------------------------------------------
__global__ __launch_bounds__(64, 1) void scan_f32_kernel(const float* __restrict__ z,
                                                         float* __restrict__ out,
                                                         float* __restrict__ cnt) {
  int row = blockIdx.x * 64 + threadIdx.x;
  const float4* zp4 = (const float4*)(z + (size_t)row * T_);
  float4* op4 = (float4*)(out + (size_t)row * T_);

  float u = 0.f, v = 0.f, carry = 0.f;
  int ci = 0;
  float4 buf[4][16];

#pragma unroll
  for (int i = 0; i < 16; i++) buf[0][i] = zp4[i];
#pragma unroll
  for (int i = 0; i < 16; i++) buf[1][i] = zp4[16 + i];

#pragma unroll 4
  for (int g = 0; g < 32; g++) {
    int gl = g + 2 > 31 ? 31 : g + 2;
#pragma unroll
    for (int i = 0; i < 16; i++) buf[(g + 2) & 3][i] = zp4[gl * 16 + i];

#pragma unroll
    for (int i = 0; i < 16; i++) {
      float4 cv = buf[g & 3][i];
      float zv[4] = {cv.x, cv.y, cv.z, cv.w};
      float ov[4];
#pragma unroll
      for (int j = 0; j < 4; j++) {
        ov[j] = carry;
        ci += (carry > 0.5f) ? 1 : 0;
        u = addrn(mulrn(ALPHA_I_, u), zv[j]);
        v = addrn(mulrn(ALPHA_V_, v), u);
        bool sb = (v >= THETA_);
        v = sb ? 0.f : v;
        carry = sb ? 1.f : 0.f;
      }
      op4[g * 16 + i] = make_float4(ov[0], ov[1], ov[2], ov[3]);
    }
  }

  float c = (float)ci;
  for (int off = 32; off; off >>= 1) c += __shfl_down(c, off, 64);
  if (threadIdx.x == 0) atomicAdd(cnt, c);
}

// ---------------------------------------------------------------------------
extern "C" void kernel_launch(void* const* d_in, const int* in_sizes, int n_in,
                              void* d_out, int out_size, void* d_ws, size_t ws_size,
                              hipStream_t stream) {
  (void)in_sizes; (void)n_in; (void)out_size; (void)ws_size;
  const float* spike  = (const float*)d_in[0];
  const float* fc1_v  = (const float*)d_in[1];
  const float* fc1_g  = (const float*)d_in[2];
  const float* fc2_v  = (const float*)d_in[3];
  const float* fc2_g  = (const float*)d_in[4];
  const float* fc3_v  = (const float*)d_in[5];
  const float* fc3_g  = (const float*)d_in[6];
  const float* delay1 = (const float*)d_in[7];
  const float* delay2 = (const float*)d_in[8];
  float* out = (float*)d_out;

  float* ws    = (float*)d_ws;
  float* w1s   = ws;                          // [0, 2048)
  float* w2sT  = ws + 2048;                   // [2048, 18432)  transposed [c][o]
  float* w3sT  = ws + 18432;                  // [18432, 19072) transposed [c][o]
  float4* efo1 = (float4*)(ws + 19072);       // 128 float4, 16B-aligned
  float4* efo2 = (float4*)(ws + 19584);       // 128 float4
  float* zbuf  = ws + 20480;                  // B*NH*T floats
  uint32_t* sbits = (uint32_t*)(zbuf + (size_t)B_ * NH_ * T_);  // B*NH*68 u32
  float* counts = out + (size_t)B_ * NOUT_ * T_;

  prep_kernel<<<1, 128, 0, stream>>>(fc1_v, fc1_g, fc2_v, fc2_g, fc3_v, fc3_g,
                                     delay1, delay2, w1s, w2sT, w3sT, efo1, efo2, counts);

  // layer 1
  gemm1_kernel<<<dim3(T_ / 256, B_), 256, 0, stream>>>(spike, w1s, zbuf);
  scan_bits_kernel<<<dim3(B_ * NH_ / 64), 64, 0, stream>>>(zbuf, sbits, counts + 0);

  // layer 2 (axon delay 1 fused into bit gather)
  gemm_delay_bits2_kernel<32><<<dim3(T_ / 512, NH_ / 32, B_), 256, 0, stream>>>(
      sbits, w2sT, efo1, zbuf, NH_);
  scan_bits_kernel<<<dim3(B_ * NH_ / 64), 64, 0, stream>>>(zbuf, sbits, counts + 1);

  // layer 3 (axon delay 2 fused into bit gather)
  gemm_delay_bits2_kernel<5><<<dim3(T_ / 512, 1, B_), 256, 0, stream>>>(
      sbits, w3sT, efo2, zbuf, NOUT_);
  scan_f32_kernel<<<dim3(B_ * NOUT_ / 64), 64, 0, stream>>>(zbuf, out, counts + 2);
}

// Round 4
// 352.125 us; speedup vs baseline: 1.2011x; 1.2011x over previous
//
#include <hip/hip_runtime.h>
#include <cstdint>

#define B_    128
#define T_    2048
#define NIN_  16
#define NH_   128
#define NOUT_ 5

#define ALPHA_I_ 0.75f
#define ALPHA_V_ 0.96875f
#define THETA_   64.0f

#define SB_STRIDE_ 68   // u32 words per (b,c) spike-bit row: 2 guard + 64 data + 2 guard

typedef short bf16x8 __attribute__((ext_vector_type(8)));
typedef float f32x16 __attribute__((ext_vector_type(16)));

__device__ __forceinline__ float mulrn(float a, float b) { return __fmul_rn(a, b); }
__device__ __forceinline__ float addrn(float a, float b) { return __fadd_rn(a, b); }

__device__ __forceinline__ uint16_t f2bf(float x) {  // RNE f32->bf16
  uint32_t u = __float_as_uint(x);
  return (uint16_t)((u + 0x7FFFu + ((u >> 16) & 1u)) >> 16);
}

// ---------------------------------------------------------------------------
// prep: weight_norm (x64 folded). Layer2 weights split into Wf=w*f, Wof=w*(1-f)
// (delay-1 interpolation folded into weights), bf16, stored PRE-SWIZZLED in
// mfma_32x32x16 A-fragment order. Layer3 stored as w3T[c][0..4]=w, [5]=f2,
// [6]=1-f2. efo tables give e=floor(d)+1 (includes delay_shift1's +1).
// ---------------------------------------------------------------------------
__global__ void prep_kernel(const float* __restrict__ fc1_v, const float* __restrict__ fc1_g,
                            const float* __restrict__ fc2_v, const float* __restrict__ fc2_g,
                            const float* __restrict__ fc3_v, const float* __restrict__ fc3_g,
                            const float* __restrict__ delay1, const float* __restrict__ delay2,
                            float* __restrict__ w1s, uint16_t* __restrict__ wswz,
                            float* __restrict__ w3T,
                            float4* __restrict__ efo1, float4* __restrict__ efo2,
                            float* __restrict__ counts) {
  int tid = threadIdx.x;
  if (tid < NH_) {
    // layer 1 row (kept [o][c] for gemm1)
    {
      float ss = 0.f;
      for (int c = 0; c < NIN_; c++) { float v = fc1_v[tid * NIN_ + c]; ss = __fmaf_rn(v, v, ss); }
      float nrm = sqrtf(ss);
      float g = fc1_g[tid];
      for (int c = 0; c < NIN_; c++)
        w1s[tid * NIN_ + c] = 64.0f * __fdiv_rn(mulrn(g, fc1_v[tid * NIN_ + c]), nrm);
    }
    // layer 2 row -> swizzled bf16 Wf / Wof
    {
      int o = tid;
      float ss = 0.f;
      for (int c = 0; c < NH_; c++) { float v = fc2_v[o * NH_ + c]; ss = __fmaf_rn(v, v, ss); }
      float nrm = sqrtf(ss);
      float g = fc2_g[o];
      int mt = o >> 5;
      for (int c = 0; c < NH_; c++) {
        float wv = 64.0f * __fdiv_rn(mulrn(g, fc2_v[o * NH_ + c]), nrm);
        float d1 = delay1[c];
        float f = __fsub_rn(d1, floorf(d1));
        float omf = __fsub_rn(1.0f, f);
        int lane = (o & 31) + 32 * ((c >> 3) & 1);
        int ks = c >> 4, j = c & 7;
        wswz[((size_t)((0 * 4 + mt) * 8 + ks) * 64 + lane) * 8 + j] = f2bf(__fmul_rn(wv, f));
        wswz[((size_t)((1 * 4 + mt) * 8 + ks) * 64 + lane) * 8 + j] = f2bf(__fmul_rn(wv, omf));
      }
    }
    // delay tables (e = floor(d)+1)
    {
      float d1 = delay1[tid];
      float fl = floorf(d1);
      float f = __fsub_rn(d1, fl);
      efo1[tid] = make_float4(__int_as_float((int)fl + 1), f, __fsub_rn(1.0f, f), 0.f);
      float d2 = delay2[tid];
      float fl2 = floorf(d2);
      float f2v = __fsub_rn(d2, fl2);
      efo2[tid] = make_float4(__int_as_float((int)fl2 + 1), f2v, __fsub_rn(1.0f, f2v), 0.f);
      // layer-3 per-c interp factors
      w3T[tid * 8 + 5] = f2v;
      w3T[tid * 8 + 6] = __fsub_rn(1.0f, f2v);
      w3T[tid * 8 + 7] = 0.f;
    }
  }
  if (tid < NOUT_) {
    float ss = 0.f;
    for (int c = 0; c < NH_; c++) { float v = fc3_v[tid * NH_ + c]; ss = __fmaf_rn(v, v, ss); }
    float nrm = sqrtf(ss);
    float g = fc3_g[tid];
    for (int c = 0; c < NH_; c++)
      w3T[c * 8 + tid] = 64.0f * __fdiv_rn(mulrn(g, fc3_v[tid * NH_ + c]), nrm);
  }
  if (tid < 3) counts[tid] = 0.f;
}

// ---------------------------------------------------------------------------
// gemm1: z[b,o,t] = sum_c w1s[o,c] * x[b,c,t]
// ---------------------------------------------------------------------------
__global__ __launch_bounds__(256) void gemm1_kernel(const float* __restrict__ x,
                                                    const float* __restrict__ w1s,
                                                    float* __restrict__ z) {
  __shared__ float w[NH_ * NIN_];
  int tid = threadIdx.x;
  for (int i = tid; i < NH_ * NIN_; i += 256) w[i] = w1s[i];
  __syncthreads();
  int t = blockIdx.x * 256 + tid;
  int b = blockIdx.y;
  const float* xp = x + (size_t)b * NIN_ * T_ + t;
  float xv[NIN_];
#pragma unroll
  for (int c = 0; c < NIN_; c++) xv[c] = xp[(size_t)c * T_];
  float* zp = z + (size_t)b * NH_ * T_ + t;
  for (int o = 0; o < NH_; o++) {
    float acc = 0.f;
#pragma unroll
    for (int c = 0; c < NIN_; c++) acc = __fmaf_rn(w[o * NIN_ + c], xv[c], acc);
    zp[(size_t)o * T_] = acc;
  }
}

// ---------------------------------------------------------------------------
// Loihi scan, bitpacked u32 output (UNSHIFTED, guarded stride-68 rows).
// count = popcount(all bits) - bit[T-1].
// ---------------------------------------------------------------------------
__global__ __launch_bounds__(64, 1) void scan_bits_kernel(const float* __restrict__ z,
                                                          uint32_t* __restrict__ sbits,
                                                          float* __restrict__ cnt) {
  int row = blockIdx.x * 64 + threadIdx.x;
  const float4* zp4 = (const float4*)(z + (size_t)row * T_);
  uint32_t* sp = sbits + (size_t)row * SB_STRIDE_;

  *(uint2*)sp = make_uint2(0u, 0u);
  *(uint2*)(sp + 66) = make_uint2(0u, 0u);
  uint2* dp = (uint2*)(sp + 2);

  float u = 0.f, v = 0.f;
  int ci = 0;
  unsigned long long mlast = 0;
  float4 buf[4][16];

#pragma unroll
  for (int i = 0; i < 16; i++) buf[0][i] = zp4[i];
#pragma unroll
  for (int i = 0; i < 16; i++) buf[1][i] = zp4[16 + i];

#pragma unroll 4
  for (int g = 0; g < 32; g++) {
    int gl = g + 2 > 31 ? 31 : g + 2;
#pragma unroll
    for (int i = 0; i < 16; i++) buf[(g + 2) & 3][i] = zp4[gl * 16 + i];

    unsigned long long m = 0;
#pragma unroll
    for (int i = 0; i < 16; i++) {
      float4 cv = buf[g & 3][i];
      float zv[4] = {cv.x, cv.y, cv.z, cv.w};
#pragma unroll
      for (int j = 0; j < 4; j++) {
        u = addrn(mulrn(ALPHA_I_, u), zv[j]);
        v = addrn(mulrn(ALPHA_V_, v), u);
        bool sb = (v >= THETA_);
        v = sb ? 0.f : v;
        m |= sb ? (1ull << (i * 4 + j)) : 0ull;
      }
    }
    dp[g] = make_uint2((uint32_t)m, (uint32_t)(m >> 32));
    ci += __popcll(m);
    mlast = m;
  }
  ci -= (int)(mlast >> 63);

  float c = (float)ci;
  for (int off = 32; off; off >>= 1) c += __shfl_down(c, off, 64);
  if (threadIdx.x == 0) atomicAdd(cnt, c);
}

// ---------------------------------------------------------------------------
// bit transpose + delay pre-shift: PTpad[b][1+t] row = 128 bits, bit c =
// s[c][t - e_c]; PTpad[b][0] = 0. One block per b; sbits rows staged in LDS.
// ---------------------------------------------------------------------------
__global__ __launch_bounds__(256) void transpose_kernel(const uint32_t* __restrict__ sbits,
                                                        const float4* __restrict__ efo,
                                                        uint32_t* __restrict__ PTpad) {
  __shared__ uint32_t rows[NH_ * SB_STRIDE_];  // 34.8 KB
  int tid = threadIdx.x;
  int b = blockIdx.x;
  const uint32_t* src = sbits + (size_t)b * NH_ * SB_STRIDE_;
  for (int i = tid; i < NH_ * SB_STRIDE_; i += 256) rows[i] = src[i];
  __syncthreads();

  uint4* outp = (uint4*)PTpad + (size_t)b * (T_ + 1);
  if (tid == 0) outp[0] = make_uint4(0u, 0u, 0u, 0u);

  int t0 = tid * 8;
  uint32_t wacc[8][4];
#pragma unroll
  for (int i = 0; i < 8; i++)
#pragma unroll
    for (int j = 0; j < 4; j++) wacc[i][j] = 0u;

#pragma unroll
  for (int c = 0; c < NH_; c++) {
    int e = __float_as_int(efo[c].x);     // uniform -> scalar load
    int bitpos0 = t0 - e;                 // for t0..t0+7: bitpos0..bitpos0+7
    int wi = bitpos0 >> 5;                // arithmetic shift, in [-1, 63]
    int sh = bitpos0 & 31;
    uint32_t lo = rows[c * SB_STRIDE_ + 2 + wi];
    uint32_t hi = rows[c * SB_STRIDE_ + 3 + wi];
    uint32_t bits8 = (uint32_t)(((((unsigned long long)hi << 32) | lo) >> sh)) & 0xFFu;
#pragma unroll
    for (int i = 0; i < 8; i++)
      wacc[i][c >> 5] |= ((bits8 >> i) & 1u) << (c & 31);
  }

#pragma unroll
  for (int i = 0; i < 8; i++)
    outp[1 + t0 + i] = make_uint4(wacc[i][0], wacc[i][1], wacc[i][2], wacc[i][3]);
}

// ---------------------------------------------------------------------------
// gemm2 via MFMA bf16: z = Wf*b0 + Wof*b1, binary b from pre-shifted PT rows.
// Wave = one 32-t column (all 128 o). Per K-step: byte-extract from the
// 128-bit rows, LUT(byte)->8x bf16 frag (ds_read_b128), 8 MFMA 32x32x16.
// grid: B*T/32/4 blocks of 256 (4 waves).
// ---------------------------------------------------------------------------
__global__ __launch_bounds__(256) void gemm2_mfma_kernel(const uint16_t* __restrict__ wswz,
                                                         const uint32_t* __restrict__ PTpad,
                                                         float* __restrict__ z) {
  __shared__ uint16_t s_w[2 * 4 * 8 * 64 * 8];  // 64 KB, A-fragment order
  __shared__ uint32_t s_lut[256 * 4];           // byte -> 8 bf16 (16B)
  int tid = threadIdx.x;

  {
    const uint4* wsrc = (const uint4*)wswz;
    uint4* wdst = (uint4*)s_w;
    for (int i = tid; i < 4096; i += 256) wdst[i] = wsrc[i];
  }
  if (tid < 256) {
#pragma unroll
    for (int j = 0; j < 4; j++) {
      uint32_t w = 0;
      if ((tid >> (2 * j)) & 1) w |= 0x3F80u;
      if ((tid >> (2 * j + 1)) & 1) w |= 0x3F800000u;
      s_lut[tid * 4 + j] = w;
    }
  }
  __syncthreads();

  int wave = tid >> 6, lane = tid & 63;
  int col = blockIdx.x * 4 + wave;   // 0 .. B*T/32-1
  int b = col >> 6;                  // T/32 = 64 columns per batch
  int tc = col & 63;
  int t = tc * 32 + (lane & 31);
  int hi = lane >> 5;

  const uint4* pt = (const uint4*)PTpad + (size_t)b * (T_ + 1);
  uint4 R0 = pt[t];      // tap s[t-e-1]  (pairs with Wf)
  uint4 R1 = pt[t + 1];  // tap s[t-e]    (pairs with Wof)
  uint32_t r0w[4] = {R0.x, R0.y, R0.z, R0.w};
  uint32_t r1w[4] = {R1.x, R1.y, R1.z, R1.w};

  f32x16 acc[4];
#pragma unroll
  for (int mt = 0; mt < 4; mt++)
#pragma unroll
    for (int r = 0; r < 16; r++) acc[mt][r] = 0.f;

  const bf16x8* swf = (const bf16x8*)s_w;
  const bf16x8* lutv = (const bf16x8*)s_lut;

#pragma unroll
  for (int ks = 0; ks < 8; ks++) {
    int sh = 16 * (ks & 1) + 8 * hi;
    uint32_t byte0 = (r0w[ks >> 1] >> sh) & 0xFFu;
    uint32_t byte1 = (r1w[ks >> 1] >> sh) & 0xFFu;
    bf16x8 bf0 = lutv[byte0];
    bf16x8 bf1 = lutv[byte1];
#pragma unroll
    for (int mt = 0; mt < 4; mt++) {
      acc[mt] = __builtin_amdgcn_mfma_f32_32x32x16_bf16(
          swf[((size_t)((0 * 4 + mt) * 8 + ks) * 64) + lane], bf0, acc[mt], 0, 0, 0);
      acc[mt] = __builtin_amdgcn_mfma_f32_32x32x16_bf16(
          swf[((size_t)((1 * 4 + mt) * 8 + ks) * 64) + lane], bf1, acc[mt], 0, 0, 0);
    }
  }

  float* zb = z + (size_t)b * NH_ * T_;
#pragma unroll
  for (int mt = 0; mt < 4; mt++)
#pragma unroll
    for (int r = 0; r < 16; r++) {
      int o = mt * 32 + (r & 3) + 8 * (r >> 2) + 4 * hi;
      zb[(size_t)o * T_ + tc * 32 + (lane & 31)] = acc[mt][r];
    }
}

// ---------------------------------------------------------------------------
// gemm3 (vector): 5 outputs, bits from pre-shifted PT2 rows, weights+interp
// factors via uniform scalar loads of w3T[c][0..6].
// ---------------------------------------------------------------------------
__global__ __launch_bounds__(256) void gemm3_kernel(const uint32_t* __restrict__ PTpad,
                                                    const float* __restrict__ w3T,
                                                    float* __restrict__ z) {
  int tid = threadIdx.x;
  int t = blockIdx.x * 256 + tid;
  int b = blockIdx.y;
  const uint4* pt = (const uint4*)PTpad + (size_t)b * (T_ + 1);
  uint4 R0 = pt[t];
  uint4 R1 = pt[t + 1];
  uint32_t r0w[4] = {R0.x, R0.y, R0.z, R0.w};
  uint32_t r1w[4] = {R1.x, R1.y, R1.z, R1.w};

  float acc[NOUT_];
#pragma unroll
  for (int o = 0; o < NOUT_; o++) acc[o] = 0.f;

#pragma unroll
  for (int c = 0; c < NH_; c++) {
    const float* wc = w3T + (c << 3);       // uniform -> s_load
    float f = wc[5], omf = wc[6];
    float fb0 = (float)((r0w[c >> 5] >> (c & 31)) & 1u);
    float fb1 = (float)((r1w[c >> 5] >> (c & 31)) & 1u);
    float val = __fmaf_rn(omf, fb1, __fmul_rn(f, fb0));
#pragma unroll
    for (int o = 0; o < NOUT_; o++) acc[o] = __fmaf_rn(wc[o], val, acc[o]);
  }

#pragma unroll
  for (int o = 0; o < NOUT_; o++)
    z[((size_t)b * NOUT_ + o) * T_ + t] = acc[o];
}

// ---------------------------------------------------------------------------
// Loihi scan, f32 SHIFTED output straight into d_out (layer 3).
// ---------------------------------------------------------------------------
__global__ __launch_bounds__(64, 1) void scan_f32_kernel(const float* __restrict__ z,
                                                         float* __restrict__ out,
                                                         float* __restrict__ cnt) {
  int row = blockIdx.x * 64 + threadIdx.x;
  const float4* zp4 = (const float4*)(z + (size_t)row * T_);
  float4* op4 = (float4*)(out + (size_t)row * T_);

  float u = 0.f, v = 0.f, carry = 0.f;
  int ci = 0;
  float4 buf[4][16];

#pragma unroll
  for (int i = 0; i < 16; i++) buf[0][i] = zp4[i];
#pragma unroll
  for (int i = 0; i < 16; i++) buf[1][i] = zp4[16 + i];

#pragma unroll 4
  for (int g = 0; g < 32; g++) {
    int gl = g + 2 > 31 ? 31 : g + 2;
#pragma unroll
    for (int i = 0; i < 16; i++) buf[(g + 2) & 3][i] = zp4[gl * 16 + i];

#pragma unroll
    for (int i = 0; i < 16; i++) {
      float4 cv = buf[g & 3][i];
      float zv[4] = {cv.x, cv.y, cv.z, cv.w};
      float ov[4];
#pragma unroll
      for (int j = 0; j < 4; j++) {
        ov[j] = carry;
        ci += (carry > 0.5f) ? 1 : 0;
        u = addrn(mulrn(ALPHA_I_, u), zv[j]);
        v = addrn(mulrn(ALPHA_V_, v), u);
        bool sb = (v >= THETA_);
        v = sb ? 0.f : v;
        carry = sb ? 1.f : 0.f;
      }
      op4[g * 16 + i] = make_float4(ov[0], ov[1], ov[2], ov[3]);
    }
  }

  float c = (float)ci;
  for (int off = 32; off; off >>= 1) c += __shfl_down(c, off, 64);
  if (threadIdx.x == 0) atomicAdd(cnt, c);
}

// ---------------------------------------------------------------------------
extern "C" void kernel_launch(void* const* d_in, const int* in_sizes, int n_in,
                              void* d_out, int out_size, void* d_ws, size_t ws_size,
                              hipStream_t stream) {
  (void)in_sizes; (void)n_in; (void)out_size; (void)ws_size;
  const float* spike  = (const float*)d_in[0];
  const float* fc1_v  = (const float*)d_in[1];
  const float* fc1_g  = (const float*)d_in[2];
  const float* fc2_v  = (const float*)d_in[3];
  const float* fc2_g  = (const float*)d_in[4];
  const float* fc3_v  = (const float*)d_in[5];
  const float* fc3_g  = (const float*)d_in[6];
  const float* delay1 = (const float*)d_in[7];
  const float* delay2 = (const float*)d_in[8];
  float* out = (float*)d_out;

  float* ws    = (float*)d_ws;
  float* w1s   = ws;                           // [0, 2048) f32
  float* w3T   = ws + 2048;                    // [2048, 3072) f32 (c-major, 8/row)
  float4* efo1 = (float4*)(ws + 3072);         // 128 float4
  float4* efo2 = (float4*)(ws + 3584);         // 128 float4
  uint16_t* wswz = (uint16_t*)(ws + 4096);     // 64 KB bf16 swizzled Wf|Wof
  float* zbuf  = ws + 20480;                   // B*NH*T f32 (134.2 MB)
  uint32_t* sbits = (uint32_t*)(zbuf + (size_t)B_ * NH_ * T_);          // 4.46 MB
  uint32_t* PTpad = sbits + (size_t)B_ * NH_ * SB_STRIDE_;              // 4.20 MB
  float* counts = out + (size_t)B_ * NOUT_ * T_;

  prep_kernel<<<1, 128, 0, stream>>>(fc1_v, fc1_g, fc2_v, fc2_g, fc3_v, fc3_g,
                                     delay1, delay2, w1s, wswz, w3T, efo1, efo2, counts);

  // layer 1
  gemm1_kernel<<<dim3(T_ / 256, B_), 256, 0, stream>>>(spike, w1s, zbuf);
  scan_bits_kernel<<<dim3(B_ * NH_ / 64), 64, 0, stream>>>(zbuf, sbits, counts + 0);
  transpose_kernel<<<dim3(B_), 256, 0, stream>>>(sbits, efo1, PTpad);

  // layer 2 (MFMA, delay folded into weights + pre-shifted bits)
  gemm2_mfma_kernel<<<dim3(B_ * T_ / 32 / 4), 256, 0, stream>>>(wswz, PTpad, zbuf);
  scan_bits_kernel<<<dim3(B_ * NH_ / 64), 64, 0, stream>>>(zbuf, sbits, counts + 1);
  transpose_kernel<<<dim3(B_), 256, 0, stream>>>(sbits, efo2, PTpad);

  // layer 3 (vector, bits from pre-shifted rows)
  gemm3_kernel<<<dim3(T_ / 256, B_), 256, 0, stream>>>(PTpad, w3T, zbuf);
  scan_f32_kernel<<<dim3(B_ * NOUT_ / 64), 64, 0, stream>>>(zbuf, out, counts + 2);
}

// Round 5
// 280.463 us; speedup vs baseline: 1.5080x; 1.2555x over previous
//
#include <hip/hip_runtime.h>
#include <cstdint>

#define B_    128
#define T_    2048
#define NIN_  16
#define NH_   128
#define NOUT_ 5

#define ALPHA_I_ 0.75f
#define ALPHA_V_ 0.96875f
#define THETA_   64.0f

#define NCHUNK_ 8
#define CHT_    256     // data timesteps per chunk
#define WARM_   96      // warmup timesteps (3 sub-chunks of 32)

typedef short bf16x8 __attribute__((ext_vector_type(8)));
typedef float f32x16 __attribute__((ext_vector_type(16)));

__device__ __forceinline__ float mulrn(float a, float b) { return __fmul_rn(a, b); }
__device__ __forceinline__ float addrn(float a, float b) { return __fadd_rn(a, b); }

__device__ __forceinline__ uint16_t f2bf(float x) {  // RNE f32->bf16
  uint32_t u = __float_as_uint(x);
  return (uint16_t)((u + 0x7FFFu + ((u >> 16) & 1u)) >> 16);
}

// ---------------------------------------------------------------------------
// prep: weight_norm (x64 folded). Layer1 weights bf16 swizzled into
// mfma_32x32x16 A-fragment order (K=16). Layer2 split Wf=w*f, Wof=w*(1-f)
// (axon-delay interp folded into weights), bf16, A-fragment order (R4 layout,
// verified). Layer3 w3T[c][0..4]=w, [5]=f2, [6]=1-f2. efo: e=floor(d)+1
// (includes delay_shift1's +1). Zero the 3 count slots.
// ---------------------------------------------------------------------------
__global__ void prep_kernel(const float* __restrict__ fc1_v, const float* __restrict__ fc1_g,
                            const float* __restrict__ fc2_v, const float* __restrict__ fc2_g,
                            const float* __restrict__ fc3_v, const float* __restrict__ fc3_g,
                            const float* __restrict__ delay1, const float* __restrict__ delay2,
                            uint16_t* __restrict__ w1swz, uint16_t* __restrict__ wswz,
                            float* __restrict__ w3T,
                            float4* __restrict__ efo1, float4* __restrict__ efo2,
                            float* __restrict__ counts) {
  int tid = threadIdx.x;
  if (tid < NH_) {
    // layer 1 row -> swizzled bf16 A-frag
    {
      float ss = 0.f;
      for (int c = 0; c < NIN_; c++) { float vv = fc1_v[tid * NIN_ + c]; ss = __fmaf_rn(vv, vv, ss); }
      float nrm = sqrtf(ss);
      float g = fc1_g[tid];
      int mt = tid >> 5;
      for (int c = 0; c < NIN_; c++) {
        float wv = 64.0f * __fdiv_rn(mulrn(g, fc1_v[tid * NIN_ + c]), nrm);
        int lane = (tid & 31) + 32 * ((c >> 3) & 1);
        int j = c & 7;
        w1swz[(mt * 64 + lane) * 8 + j] = f2bf(wv);
      }
    }
    // layer 2 row -> swizzled bf16 Wf / Wof (R4-verified layout)
    {
      int o = tid;
      float ss = 0.f;
      for (int c = 0; c < NH_; c++) { float vv = fc2_v[o * NH_ + c]; ss = __fmaf_rn(vv, vv, ss); }
      float nrm = sqrtf(ss);
      float g = fc2_g[o];
      int mt = o >> 5;
      for (int c = 0; c < NH_; c++) {
        float wv = 64.0f * __fdiv_rn(mulrn(g, fc2_v[o * NH_ + c]), nrm);
        float d1 = delay1[c];
        float f = __fsub_rn(d1, floorf(d1));
        float omf = __fsub_rn(1.0f, f);
        int lane = (o & 31) + 32 * ((c >> 3) & 1);
        int ks = c >> 4, j = c & 7;
        wswz[((size_t)((0 * 4 + mt) * 8 + ks) * 64 + lane) * 8 + j] = f2bf(__fmul_rn(wv, f));
        wswz[((size_t)((1 * 4 + mt) * 8 + ks) * 64 + lane) * 8 + j] = f2bf(__fmul_rn(wv, omf));
      }
    }
    // delay tables
    {
      float d1 = delay1[tid];
      float fl = floorf(d1);
      float f = __fsub_rn(d1, fl);
      efo1[tid] = make_float4(__int_as_float((int)fl + 1), f, __fsub_rn(1.0f, f), 0.f);
      float d2 = delay2[tid];
      float fl2 = floorf(d2);
      float f2v = __fsub_rn(d2, fl2);
      efo2[tid] = make_float4(__int_as_float((int)fl2 + 1), f2v, __fsub_rn(1.0f, f2v), 0.f);
      w3T[tid * 8 + 5] = f2v;
      w3T[tid * 8 + 6] = __fsub_rn(1.0f, f2v);
      w3T[tid * 8 + 7] = 0.f;
    }
  }
  if (tid < NOUT_) {
    float ss = 0.f;
    for (int c = 0; c < NH_; c++) { float vv = fc3_v[tid * NH_ + c]; ss = __fmaf_rn(vv, vv, ss); }
    float nrm = sqrtf(ss);
    float g = fc3_g[tid];
    for (int c = 0; c < NH_; c++)
      w3T[c * 8 + tid] = 64.0f * __fdiv_rn(mulrn(g, fc3_v[tid * NH_ + c]), nrm);
  }
  if (tid < 3) counts[tid] = 0.f;
}

// ---------------------------------------------------------------------------
// pack: input f32 spikes (B,16,T) -> 16-bit channel masks Xb[b][t] via ballot.
// wave = (b, 64-t group); coalesced reads per channel + coalesced u16 store.
// ---------------------------------------------------------------------------
__global__ __launch_bounds__(256) void pack_kernel(const float* __restrict__ spike,
                                                   uint16_t* __restrict__ Xb) {
  int gw = blockIdx.x * 4 + (threadIdx.x >> 6);  // 0 .. B*T/64-1
  int lane = threadIdx.x & 63;
  int b = gw >> 5;                                // T/64 = 32 groups per b
  int t = (gw & 31) * 64 + lane;
  const float* sp = spike + (size_t)b * NIN_ * T_ + t;
  uint32_t mask = 0;
#pragma unroll
  for (int c = 0; c < NIN_; c++) {
    unsigned long long bal = __ballot(sp[(size_t)c * T_] != 0.f);
    mask |= (uint32_t)((bal >> lane) & 1ull) << c;
  }
  Xb[(size_t)b * T_ + t] = (uint16_t)mask;
}

// ---------------------------------------------------------------------------
// Fused layer 1: MFMA gemm (K=16, weights bf16 in regs, bits->bf16 via LDS
// LUT) -> z tile in LDS [o][33] -> in-LDS Loihi scan (128 threads, chunked T
// with 96-step warmup) -> bitpacked words to sbits2[b][slot][o] + popcounts.
// grid (NCHUNK_, B), block 256 (4 waves = 4 o-tiles).
// ---------------------------------------------------------------------------
__global__ __launch_bounds__(256) void fused_layer1(const uint16_t* __restrict__ Xb,
                                                    const uint16_t* __restrict__ w1swz,
                                                    uint32_t* __restrict__ sbits2,
                                                    float* __restrict__ cnt) {
  __shared__ float zt[NH_ * 33];
  __shared__ uint32_t s_lut[256 * 4];
  int tid = threadIdx.x;
  int wv = tid >> 6, lane = tid & 63;
  int hi = lane >> 5, tl = lane & 31;
  int ci = blockIdx.x, b = blockIdx.y;
  {
    int e = tid;
#pragma unroll
    for (int j = 0; j < 4; j++) {
      uint32_t w = 0;
      if ((e >> (2 * j)) & 1) w |= 0x3F80u;
      if ((e >> (2 * j + 1)) & 1) w |= 0x3F800000u;
      s_lut[e * 4 + j] = w;
    }
  }
  bf16x8 wfrag = ((const bf16x8*)w1swz)[wv * 64 + lane];
  __syncthreads();

  int wch = (ci == 0) ? 0 : (WARM_ / 32);
  int nch = CHT_ / 32 + wch;
  int chbase0 = ci * CHT_ - wch * 32;
  const uint16_t* xb = Xb + (size_t)b * T_;
  uint32_t* sb = sbits2 + (size_t)b * 68 * NH_;

  float u = 0.f, v = 0.f;
  int cnt_i = 0;
  uint16_t xcur = xb[chbase0 + tl];
  for (int g = 0; g < nch; g++) {
    int chbase = chbase0 + g * 32;
    uint16_t xnext = (g + 1 < nch) ? xb[chbase + 32 + tl] : (uint16_t)0;
    uint32_t byt = (uint32_t)(xcur >> (8 * hi)) & 0xFFu;
    bf16x8 bfrag = ((const bf16x8*)s_lut)[byt];
    f32x16 acc;
#pragma unroll
    for (int r = 0; r < 16; r++) acc[r] = 0.f;
    acc = __builtin_amdgcn_mfma_f32_32x32x16_bf16(wfrag, bfrag, acc, 0, 0, 0);
#pragma unroll
    for (int r = 0; r < 16; r++) {
      int o = wv * 32 + (r & 3) + 8 * (r >> 2) + 4 * hi;
      zt[o * 33 + tl] = acc[r];
    }
    __syncthreads();
    if (tid < NH_) {
      uint32_t m = 0;
#pragma unroll 8
      for (int j = 0; j < 32; j++) {
        float z = zt[tid * 33 + j];
        u = addrn(mulrn(ALPHA_I_, u), z);
        v = addrn(mulrn(ALPHA_V_, v), u);
        bool s = (v >= THETA_);
        v = s ? 0.f : v;
        m |= s ? (1u << j) : 0u;
      }
      if (g >= wch) {
        int gw = chbase >> 5;
        sb[(2 + gw) * NH_ + tid] = m;
        int pc = __popc(m);
        if (gw == 63) pc -= (int)(m >> 31);
        cnt_i += pc;
      }
    }
    __syncthreads();
    xcur = xnext;
  }
  if (tid < NH_ && ci == 0) { sb[0 * NH_ + tid] = 0u; sb[1 * NH_ + tid] = 0u; }
  if (tid < NH_ && ci == NCHUNK_ - 1) { sb[66 * NH_ + tid] = 0u; sb[67 * NH_ + tid] = 0u; }
  float c = (float)cnt_i;
  for (int off = 32; off; off >>= 1) c += __shfl_down(c, off, 64);
  if ((tid & 63) == 0 && tid < NH_) atomicAdd(cnt, c);
}

// ---------------------------------------------------------------------------
// Fused layer 2: per k-step, two taps from pre-shifted PT rows (byte-extract
// + LUT, R4-verified math) x register-resident Wf/Wof frags -> 16 MFMA ->
// LDS z tile -> in-LDS scan -> sbits2 + counts. grid (NCHUNK_, B), block 256.
// ---------------------------------------------------------------------------
__global__ __launch_bounds__(256) void fused_layer2(const uint32_t* __restrict__ PTpad,
                                                    const uint16_t* __restrict__ wswz,
                                                    uint32_t* __restrict__ sbits2,
                                                    float* __restrict__ cnt) {
  __shared__ float zt[NH_ * 33];
  __shared__ uint32_t s_lut[256 * 4];
  int tid = threadIdx.x;
  int wv = tid >> 6, lane = tid & 63;
  int hi = lane >> 5, tl = lane & 31;
  int ci = blockIdx.x, b = blockIdx.y;
  {
    int e = tid;
#pragma unroll
    for (int j = 0; j < 4; j++) {
      uint32_t w = 0;
      if ((e >> (2 * j)) & 1) w |= 0x3F80u;
      if ((e >> (2 * j + 1)) & 1) w |= 0x3F800000u;
      s_lut[e * 4 + j] = w;
    }
  }
  const bf16x8* wsv = (const bf16x8*)wswz;
  bf16x8 wf[8], wo[8];
#pragma unroll
  for (int ks = 0; ks < 8; ks++) {
    wf[ks] = wsv[((size_t)((0 * 4 + wv) * 8 + ks) * 64) + lane];
    wo[ks] = wsv[((size_t)((1 * 4 + wv) * 8 + ks) * 64) + lane];
  }
  __syncthreads();

  int wch = (ci == 0) ? 0 : (WARM_ / 32);
  int nch = CHT_ / 32 + wch;
  int chbase0 = ci * CHT_ - wch * 32;
  const uint4* pt = (const uint4*)PTpad + (size_t)b * (T_ + 1);
  uint32_t* sb = sbits2 + (size_t)b * 68 * NH_;

  float u = 0.f, v = 0.f;
  int cnt_i = 0;
  uint4 R0 = pt[chbase0 + tl];
  uint4 R1 = pt[chbase0 + tl + 1];
  for (int g = 0; g < nch; g++) {
    int chbase = chbase0 + g * 32;
    uint4 R0n = R0, R1n = R1;
    if (g + 1 < nch) { R0n = pt[chbase + 32 + tl]; R1n = pt[chbase + 33 + tl]; }
    uint32_t r0w[4] = {R0.x, R0.y, R0.z, R0.w};
    uint32_t r1w[4] = {R1.x, R1.y, R1.z, R1.w};
    f32x16 acc;
#pragma unroll
    for (int r = 0; r < 16; r++) acc[r] = 0.f;
#pragma unroll
    for (int ks = 0; ks < 8; ks++) {
      int sh = 16 * (ks & 1) + 8 * hi;
      uint32_t b0 = (r0w[ks >> 1] >> sh) & 0xFFu;
      uint32_t b1 = (r1w[ks >> 1] >> sh) & 0xFFu;
      acc = __builtin_amdgcn_mfma_f32_32x32x16_bf16(wf[ks], ((const bf16x8*)s_lut)[b0], acc, 0, 0, 0);
      acc = __builtin_amdgcn_mfma_f32_32x32x16_bf16(wo[ks], ((const bf16x8*)s_lut)[b1], acc, 0, 0, 0);
    }
#pragma unroll
    for (int r = 0; r < 16; r++) {
      int o = wv * 32 + (r & 3) + 8 * (r >> 2) + 4 * hi;
      zt[o * 33 + tl] = acc[r];
    }
    __syncthreads();
    if (tid < NH_) {
      uint32_t m = 0;
#pragma unroll 8
      for (int j = 0; j < 32; j++) {
        float z = zt[tid * 33 + j];
        u = addrn(mulrn(ALPHA_I_, u), z);
        v = addrn(mulrn(ALPHA_V_, v), u);
        bool s = (v >= THETA_);
        v = s ? 0.f : v;
        m |= s ? (1u << j) : 0u;
      }
      if (g >= wch) {
        int gw = chbase >> 5;
        sb[(2 + gw) * NH_ + tid] = m;
        int pc = __popc(m);
        if (gw == 63) pc -= (int)(m >> 31);
        cnt_i += pc;
      }
    }
    __syncthreads();
    R0 = R0n; R1 = R1n;
  }
  if (tid < NH_ && ci == 0) { sb[0 * NH_ + tid] = 0u; sb[1 * NH_ + tid] = 0u; }
  if (tid < NH_ && ci == NCHUNK_ - 1) { sb[66 * NH_ + tid] = 0u; sb[67 * NH_ + tid] = 0u; }
  float c = (float)cnt_i;
  for (int off = 32; off; off >>= 1) c += __shfl_down(c, off, 64);
  if ((tid & 63) == 0 && tid < NH_) atomicAdd(cnt, c);
}

// ---------------------------------------------------------------------------
// bit transpose + delay pre-shift: PTpad[b][1+t] row (128 bits) bit c =
// s[c][t - e_c]; PTpad[b][0] = 0. Reads sbits2[b][slot][o] layout.
// ---------------------------------------------------------------------------
__global__ __launch_bounds__(256) void transpose_kernel(const uint32_t* __restrict__ sbits2,
                                                        const float4* __restrict__ efo,
                                                        uint32_t* __restrict__ PTpad) {
  __shared__ uint32_t rows[NH_ * 69];  // [c][slot], padded
  int tid = threadIdx.x;
  int b = blockIdx.x;
  const uint32_t* src = sbits2 + (size_t)b * 68 * NH_;
  for (int i = tid; i < 68 * NH_; i += 256) {
    int w = i >> 7, c = i & 127;
    rows[c * 69 + w] = src[i];
  }
  __syncthreads();

  uint4* outp = (uint4*)PTpad + (size_t)b * (T_ + 1);
  if (tid == 0) outp[0] = make_uint4(0u, 0u, 0u, 0u);

  int t0 = tid * 8;
  uint32_t wacc[8][4];
#pragma unroll
  for (int i = 0; i < 8; i++)
#pragma unroll
    for (int j = 0; j < 4; j++) wacc[i][j] = 0u;

#pragma unroll
  for (int c = 0; c < NH_; c++) {
    int e = __float_as_int(efo[c].x);
    int bitpos0 = t0 - e;
    int wi = bitpos0 >> 5;
    int sh = bitpos0 & 31;
    uint32_t lo = rows[c * 69 + 2 + wi];
    uint32_t hi2 = rows[c * 69 + 3 + wi];
    uint32_t bits8 = (uint32_t)(((((unsigned long long)hi2 << 32) | lo) >> sh)) & 0xFFu;
#pragma unroll
    for (int i = 0; i < 8; i++)
      wacc[i][c >> 5] |= ((bits8 >> i) & 1u) << (c & 31);
  }

#pragma unroll
  for (int i = 0; i < 8; i++)
    outp[1 + t0 + i] = make_uint4(wacc[i][0], wacc[i][1], wacc[i][2], wacc[i][3]);
}

// ---------------------------------------------------------------------------
// gemm3 (vector): 5 outputs from pre-shifted PT rows (R4 verbatim).
// ---------------------------------------------------------------------------
__global__ __launch_bounds__(256) void gemm3_kernel(const uint32_t* __restrict__ PTpad,
                                                    const float* __restrict__ w3T,
                                                    float* __restrict__ z) {
  int tid = threadIdx.x;
  int t = blockIdx.x * 256 + tid;
  int b = blockIdx.y;
  const uint4* pt = (const uint4*)PTpad + (size_t)b * (T_ + 1);
  uint4 R0 = pt[t];
  uint4 R1 = pt[t + 1];
  uint32_t r0w[4] = {R0.x, R0.y, R0.z, R0.w};
  uint32_t r1w[4] = {R1.x, R1.y, R1.z, R1.w};

  float acc[NOUT_];
#pragma unroll
  for (int o = 0; o < NOUT_; o++) acc[o] = 0.f;

#pragma unroll
  for (int c = 0; c < NH_; c++) {
    const float* wc = w3T + (c << 3);
    float f = wc[5], omf = wc[6];
    float fb0 = (float)((r0w[c >> 5] >> (c & 31)) & 1u);
    float fb1 = (float)((r1w[c >> 5] >> (c & 31)) & 1u);
    float val = __fmaf_rn(omf, fb1, __fmul_rn(f, fb0));
#pragma unroll
    for (int o = 0; o < NOUT_; o++) acc[o] = __fmaf_rn(wc[o], val, acc[o]);
  }

#pragma unroll
  for (int o = 0; o < NOUT_; o++)
    z[((size_t)b * NOUT_ + o) * T_ + t] = acc[o];
}

// ---------------------------------------------------------------------------
// Chunked layer-3 scan: thread per (chunk, b, o); warmup 96; f32 SHIFTED
// output (out[t]=s[t-1]) assembled into aligned float4 stores; count excl
// t=T-1.
// ---------------------------------------------------------------------------
__global__ __launch_bounds__(256) void scan3_kernel(const float* __restrict__ z3,
                                                    float* __restrict__ out,
                                                    float* __restrict__ cnt) {
  int id = blockIdx.x * 256 + threadIdx.x;   // 0 .. NCHUNK_*B_*NOUT_-1
  int row = id % (B_ * NOUT_);
  int ci = id / (B_ * NOUT_);
  int tstart = ci * CHT_;
  int t0 = (ci == 0) ? 0 : tstart - WARM_;
  const float4* zp4 = (const float4*)(z3 + (size_t)row * T_);

  float u = 0.f, v = 0.f, carry = 0.f;
  int cnt_i = 0;
  for (int gg = t0 / 16; gg < tstart / 16; gg++) {
#pragma unroll
    for (int q = 0; q < 4; q++) {
      float4 cv = zp4[gg * 4 + q];
      float zv[4] = {cv.x, cv.y, cv.z, cv.w};
#pragma unroll
      for (int j = 0; j < 4; j++) {
        u = addrn(mulrn(ALPHA_I_, u), zv[j]);
        v = addrn(mulrn(ALPHA_V_, v), u);
        bool s = (v >= THETA_);
        v = s ? 0.f : v;
        carry = s ? 1.f : 0.f;
      }
    }
  }
  float4* op4 = (float4*)(out + (size_t)row * T_ + tstart);
  for (int gg = 0; gg < CHT_ / 16; gg++) {
    float sarr[16];
#pragma unroll
    for (int q = 0; q < 4; q++) {
      float4 cv = zp4[(tstart / 16 + gg) * 4 + q];
      float zv[4] = {cv.x, cv.y, cv.z, cv.w};
#pragma unroll
      for (int j = 0; j < 4; j++) {
        u = addrn(mulrn(ALPHA_I_, u), zv[j]);
        v = addrn(mulrn(ALPHA_V_, v), u);
        bool s = (v >= THETA_);
        v = s ? 0.f : v;
        sarr[q * 4 + j] = s ? 1.f : 0.f;
      }
    }
#pragma unroll
    for (int k = 0; k < 16; k++) {
      int t = tstart + gg * 16 + k;
      if (t < T_ - 1) cnt_i += (sarr[k] != 0.f) ? 1 : 0;
    }
    op4[gg * 4 + 0] = make_float4(carry, sarr[0], sarr[1], sarr[2]);
    op4[gg * 4 + 1] = make_float4(sarr[3], sarr[4], sarr[5], sarr[6]);
    op4[gg * 4 + 2] = make_float4(sarr[7], sarr[8], sarr[9], sarr[10]);
    op4[gg * 4 + 3] = make_float4(sarr[11], sarr[12], sarr[13], sarr[14]);
    carry = sarr[15];
  }
  float c = (float)cnt_i;
  for (int off = 32; off; off >>= 1) c += __shfl_down(c, off, 64);
  if ((threadIdx.x & 63) == 0) atomicAdd(cnt, c);
}

// ---------------------------------------------------------------------------
extern "C" void kernel_launch(void* const* d_in, const int* in_sizes, int n_in,
                              void* d_out, int out_size, void* d_ws, size_t ws_size,
                              hipStream_t stream) {
  (void)in_sizes; (void)n_in; (void)out_size; (void)ws_size;
  const float* spike  = (const float*)d_in[0];
  const float* fc1_v  = (const float*)d_in[1];
  const float* fc1_g  = (const float*)d_in[2];
  const float* fc2_v  = (const float*)d_in[3];
  const float* fc2_g  = (const float*)d_in[4];
  const float* fc3_v  = (const float*)d_in[5];
  const float* fc3_g  = (const float*)d_in[6];
  const float* delay1 = (const float*)d_in[7];
  const float* delay2 = (const float*)d_in[8];
  float* out = (float*)d_out;

  float* ws = (float*)d_ws;
  float* w3T       = ws;                         // 1024 f
  float4* efo1     = (float4*)(ws + 1024);       // 512 f
  float4* efo2     = (float4*)(ws + 1536);       // 512 f
  uint16_t* w1swz  = (uint16_t*)(ws + 2048);     // 2048 u16 = 1024 f
  uint16_t* wswz   = (uint16_t*)(ws + 3072);     // 32768 u16 = 16384 f
  uint16_t* Xb     = (uint16_t*)(ws + 19456);    // B*T u16 = 131072 f
  uint32_t* sbits2 = (uint32_t*)(ws + 150528);   // B*68*128 u32
  uint32_t* PTpad  = (uint32_t*)(ws + 1264640);  // B*(T+1)*4 u32, 16B-aligned
  float* z3        = ws + 2313728;               // B*5*T f32
  float* counts = out + (size_t)B_ * NOUT_ * T_;

  prep_kernel<<<1, 128, 0, stream>>>(fc1_v, fc1_g, fc2_v, fc2_g, fc3_v, fc3_g,
                                     delay1, delay2, w1swz, wswz, w3T, efo1, efo2, counts);

  pack_kernel<<<dim3(B_ * T_ / 64 / 4), 256, 0, stream>>>(spike, Xb);

  fused_layer1<<<dim3(NCHUNK_, B_), 256, 0, stream>>>(Xb, w1swz, sbits2, counts + 0);
  transpose_kernel<<<dim3(B_), 256, 0, stream>>>(sbits2, efo1, PTpad);

  fused_layer2<<<dim3(NCHUNK_, B_), 256, 0, stream>>>(PTpad, wswz, sbits2, counts + 1);
  transpose_kernel<<<dim3(B_), 256, 0, stream>>>(sbits2, efo2, PTpad);

  gemm3_kernel<<<dim3(T_ / 256, B_), 256, 0, stream>>>(PTpad, w3T, z3);
  scan3_kernel<<<dim3(NCHUNK_ * B_ * NOUT_ / 256), 256, 0, stream>>>(z3, out, counts + 2);
}